// Round 7
// baseline (3814.140 us; speedup 1.0000x reference)
//
#include <hip/hip_runtime.h>
#include <hip/hip_bf16.h>
#include <type_traits>

// LSTM decoder B=256, T=512, H=1024 — persistent fp16 MFMA, v11.
// v10.3 measured 2365 us; counters PROVED the XCD-local h path (WRITE 266MB->5MB).
// v11 attacks the two largest remaining costs:
//  1) B weights re-read from LDS every step (256KB/step/CU port traffic,
//     ~2000 cy in the MFMA critical path) -> B fully REGISTER-resident.
//  2) zero TLP (1 WG/CU, lockstep phases; ~60% wait) -> 2 WGs/CU overlap.
// Structure: 512 WGs x 256 threads (4 waves = K-quarters, each covering both
// m-halves); WG owns a 16-j tile (nt dimension removed -> per-wave B = 32
// fragments = 128 VGPR, exactly v8's Breg budget). Wlds deleted; LDS = 16KB
// reduction scratch only. pack_w / prep_state / h layout / barrier / spin
// budgets unchanged from v10.3. __launch_bounds__(256,2) forces <=256 regs
// (spill rather than lose 2-WG co-residency).

#define BB 256
#define TT 512
#define HH 1024

typedef __attribute__((ext_vector_type(8))) short short8;
typedef __attribute__((ext_vector_type(8))) _Float16 half8;
typedef __attribute__((ext_vector_type(4))) float float4v;

#define HP_U64 ((size_t)65536)   // u64 per h buffer: 256 U-units x 256 rows

__device__ __forceinline__ float sigf(float x) { return 1.0f / (1.0f + __expf(-x)); }
__device__ __forceinline__ float tanhff(float x) {
    return 1.0f - 2.0f / (__expf(2.0f * x) + 1.0f);
}

// ---- pack W_hh (4096x1024 f32) -> fp16 B-fragment order (UNCHANGED) ----
// Wp[jt2(32)][kc(32)][g(4)][nt(2)][lane(64)][8] ; per-jt2 block = 256 KB
__global__ __launch_bounds__(256) void pack_w(const float* __restrict__ W_hh,
                                              unsigned short* __restrict__ Wp) {
    int fid = blockIdx.x * 256 + threadIdx.x;   // 0..524287
    int lane = fid & 63;
    int nt = (fid >> 6) & 1;
    int g = (fid >> 7) & 3;
    int kc = (fid >> 9) & 31;
    int jt2 = fid >> 14;
    int j = jt2 * 32 + nt * 16 + (lane & 15);
    int row = g * HH + j;
    int k = kc * 32 + (lane >> 4) * 8;
    const float* src = W_hh + (size_t)row * HH + k;
    union { _Float16 h[8]; short8 s; } u;
#pragma unroll
    for (int e = 0; e < 8; ++e) u.h[e] = (_Float16)src[e];
    *(short8*)(Wp + (size_t)fid * 8) = u.s;
}

// ---- h0 -> fp16 fragment layout in buffer 0; zero barrier counters (UNCHANGED) ----
__global__ __launch_bounds__(256) void prep_state(const float* __restrict__ h0,
                                                  unsigned long long* __restrict__ hb0,
                                                  unsigned int* __restrict__ cnt) {
    int gid = blockIdx.x * 256 + threadIdx.x;   // 0..65535
    int r = gid & 255;
    int U = gid >> 8;
    int kb = (U >> 3) * 32 + ((U >> 1) & 3) * 8 + (U & 1) * 4;
    float4 v = *(const float4*)(h0 + (size_t)r * HH + kb);
    union { _Float16 h[4]; unsigned long long u; } x;
    x.h[0] = (_Float16)v.x; x.h[1] = (_Float16)v.y;
    x.h[2] = (_Float16)v.z; x.h[3] = (_Float16)v.w;
    hb0[(size_t)U * 256 + r] = x.u;
    if (blockIdx.x == 0) cnt[threadIdx.x] = 0;   // per-group {bar, mask, arrive}
}

// ---- persistent LSTM kernel: all 512 steps + final FC ----
__global__ __launch_bounds__(256, 2) void lstm_persist(
    const float* __restrict__ y_hist,
    const float* __restrict__ W_ih,           // (4096) flat
    const float* __restrict__ b_ih,
    const float* __restrict__ b_hh,
    const float* __restrict__ c0,             // (B,H) f32
    const float* __restrict__ W_fc,           // (H)
    const float* __restrict__ b_fc,           // (1)
    const unsigned short* __restrict__ Wp,    // packed fp16 W fragments
    unsigned long long* hbase,                // 2 buffers x HP_U64 u64
    unsigned int* cnt,
    float* __restrict__ out)
{
    __shared__ __align__(16) float scr[4096];   // 16 KB: 4 regions x 1024
    // 16 KiB LDS, <=256 VGPR -> 2 WGs/CU; grid=512 => all co-resident

    const int tid = threadIdx.x;               // 0..255
    const int lane = tid & 63;
    const int k4 = tid >> 6;                   // wave = K quarter 0..3
    const int bid = blockIdx.x;
    const int gm = bid & 7;                    // m-group == XCD id (round-robin)
    const int jt3 = bid >> 3;                  // 16-j tile 0..63
    const int ntf = jt3 & 1;

    const unsigned short* WpJ = Wp + (size_t)(jt3 >> 1) * 131072;

    // --- B fully in registers: 4 gates x K-quarter = 32 fragments (128 VGPR) ---
    half8 Breg[8][4];   // [chunk][gate]
#pragma unroll
    for (int ch = 0; ch < 8; ++ch) {
        int kc = k4 * 8 + ch;
#pragma unroll
        for (int g = 0; g < 4; ++g)
            Breg[ch][g] = *(const half8*)
                (WpJ + (size_t)((((kc * 4 + g) * 2 + ntf) * 64 + lane)) * 8);
    }

    // --- A addressing (both m halves per wave) ---
    const int q = lane >> 4;
    const size_t abase = (size_t)(gm * 2) * 16 + (lane & 15);   // mh=0; mh=1 -> +16
    const size_t qoff = (size_t)q * 512;
    const int ml = q * 4;

    // --- epilogue constants (256 threads: 1 row x 2 j each) ---
    const int em = tid & 31;                   // tile-local row
    const int jp = tid >> 5;                   // j-pair 0..7 (16 j per WG)
    const int M = gm * 32 + em;
    float wi_[4][2], bs_[4][2], c_[2];
#pragma unroll
    for (int g = 0; g < 4; ++g)
#pragma unroll
        for (int jj = 0; jj < 2; ++jj) {
            int j = jt3 * 16 + jp * 2 + jj;
            wi_[g][jj] = W_ih[g * HH + j];
            bs_[g][jj] = b_ih[g * HH + j] + b_hh[g * HH + j];
        }
#pragma unroll
    for (int jj = 0; jj < 2; ++jj)
        c_[jj] = c0[(size_t)M * HH + jt3 * 16 + jp * 2 + jj];
    // u32 store idx: U = (jt3>>1)*8 + ntf*4 + (jp>>1); wave = full 256B line
    const size_t sidx32 =
        ((size_t)((jt3 >> 1) * 8 + ntf * 4 + (jp >> 1)) * 256 + M) * 2 + (jp & 1);

    unsigned int* mycnt = cnt + gm * 32;       // [0]=barrier [1]=xcd mask [2]=arrive

    // --- spin budget: hang-proofing (v10.3-proven) ---
    unsigned spin_budget = 1u << 20;

    // --- XCD-uniformity detection (group = 64 WGs). Bailout -> SAFE path. ---
    if (tid == 0) {
        unsigned myxcd;
        asm volatile("s_getreg_b32 %0, hwreg(HW_REG_XCC_ID)" : "=s"(myxcd));
        __hip_atomic_fetch_or(mycnt + 1, 1u << (myxcd & 31u),
                              __ATOMIC_RELAXED, __HIP_MEMORY_SCOPE_AGENT);
        __hip_atomic_fetch_add(mycnt + 2, 1u,
                               __ATOMIC_RELAXED, __HIP_MEMORY_SCOPE_AGENT);
        int ok = 0;
        while (spin_budget) {
            if (__hip_atomic_load(mycnt + 2, __ATOMIC_RELAXED,
                                  __HIP_MEMORY_SCOPE_AGENT) >= 64u) { ok = 1; break; }
            __builtin_amdgcn_s_sleep(1);
            --spin_budget;
        }
        unsigned mm = __hip_atomic_load(mycnt + 1, __ATOMIC_RELAXED,
                                        __HIP_MEMORY_SCOPE_AGENT);
        ((volatile int*)scr)[0] = (ok && ((mm & (mm - 1u)) == 0u)) ? 1 : 0;
    }
    __syncthreads();
    const bool fastmode = (((volatile int*)scr)[0] != 0);
    __syncthreads();   // flag captured before scr reuse

    auto mainloop = [&](auto FASTC) {
        constexpr bool FAST = decltype(FASTC)::value;
        for (int t = 0; t < TT; ++t) {
            const unsigned long long* hR = hbase + (size_t)(t & 1) * HP_U64;
            unsigned long long* hW = hbase + (size_t)((t + 1) & 1) * HP_U64;

            float x = y_hist[(size_t)M * TT + t];   // epilogue input, prefetched

            float4v acc[8] = {{0.f,0.f,0.f,0.f},{0.f,0.f,0.f,0.f},{0.f,0.f,0.f,0.f},
                              {0.f,0.f,0.f,0.f},{0.f,0.f,0.f,0.f},{0.f,0.f,0.f,0.f},
                              {0.f,0.f,0.f,0.f},{0.f,0.f,0.f,0.f}};

            // --- K-loop: 8 chunks (K=32) in 2 batches of 4 (ring = 32 VGPR) ---
#pragma unroll
            for (int half = 0; half < 2; ++half) {
                unsigned long long ring[4][2][2];   // [p][mh][Ueven/odd]
                if constexpr (FAST) {
#pragma unroll
                    for (int p = 0; p < 4; ++p) {
                        size_t base = (size_t)(k4 * 8 + half * 4 + p) * 2048 + qoff + abase;
#pragma unroll
                        for (int mh = 0; mh < 2; ++mh) {
                            asm volatile("global_load_dwordx2 %0, %1, off sc1"
                                         : "=v"(ring[p][mh][0]) : "v"(&hR[base + mh * 16]));
                            asm volatile("global_load_dwordx2 %0, %1, off sc1"
                                         : "=v"(ring[p][mh][1]) : "v"(&hR[base + mh * 16 + 256]));
                        }
                    }
                    asm volatile("s_waitcnt vmcnt(0)" ::: "memory");
                    __builtin_amdgcn_sched_barrier(0);   // rule #18
                } else {
#pragma unroll
                    for (int p = 0; p < 4; ++p) {
                        size_t base = (size_t)(k4 * 8 + half * 4 + p) * 2048 + qoff + abase;
#pragma unroll
                        for (int mh = 0; mh < 2; ++mh) {
                            ring[p][mh][0] = __hip_atomic_load(
                                (unsigned long long*)&hR[base + mh * 16],
                                __ATOMIC_RELAXED, __HIP_MEMORY_SCOPE_AGENT);
                            ring[p][mh][1] = __hip_atomic_load(
                                (unsigned long long*)&hR[base + mh * 16 + 256],
                                __ATOMIC_RELAXED, __HIP_MEMORY_SCOPE_AGENT);
                        }
                    }
                }
#pragma unroll
                for (int p = 0; p < 4; ++p) {
                    const int ch = half * 4 + p;
                    union { unsigned long long u[2]; half8 h; } af0, af1;
                    af0.u[0] = ring[p][0][0]; af0.u[1] = ring[p][0][1];
                    af1.u[0] = ring[p][1][0]; af1.u[1] = ring[p][1][1];
#pragma unroll
                    for (int g = 0; g < 4; ++g) {
                        acc[g * 2 + 0] = __builtin_amdgcn_mfma_f32_16x16x32_f16(
                            af0.h, Breg[ch][g], acc[g * 2 + 0], 0, 0, 0);
                        acc[g * 2 + 1] = __builtin_amdgcn_mfma_f32_16x16x32_f16(
                            af1.h, Breg[ch][g], acc[g * 2 + 1], 0, 0, 0);
                    }
                }
            }

            // --- 4-way k-reduction (v8 scheme, nt->mh): regions (mh, X) x 1024 ---
            if (k4 >= 2) {
#pragma unroll
                for (int a = 0; a < 8; ++a) {
                    int g = a >> 1, mh = a & 1;
                    int n = g * 16 + (lane & 15);
                    *(float4v*)&scr[(mh * 2 + (k4 & 1)) * 1024 + n * 16 +
                                    (ml ^ ((n & 3) << 2))] = acc[a];
                }
            }
            __syncthreads();
            if (k4 < 2) {
#pragma unroll
                for (int a = 0; a < 8; ++a) {
                    int g = a >> 1, mh = a & 1;
                    int n = g * 16 + (lane & 15);
                    acc[a] += *(const float4v*)&scr[(mh * 2 + k4) * 1024 + n * 16 +
                                                    (ml ^ ((n & 3) << 2))];
                }
                if (k4 == 1) {
#pragma unroll
                    for (int a = 0; a < 8; ++a) {
                        int g = a >> 1, mh = a & 1;
                        int n = g * 16 + (lane & 15);
                        *(float4v*)&scr[(mh * 2 + 1) * 1024 + n * 16 +
                                        (ml ^ ((n & 3) << 2))] = acc[a];
                    }
                }
            }
            __syncthreads();
            if (k4 == 0) {
#pragma unroll
                for (int a = 0; a < 8; ++a) {
                    int g = a >> 1, mh = a & 1;
                    int n = g * 16 + (lane & 15);
                    int sw = n * 16 + (ml ^ ((n & 3) << 2));
                    acc[a] += *(const float4v*)&scr[(mh * 2 + 1) * 1024 + sw];
                    *(float4v*)&scr[(mh * 2) * 1024 + sw] = acc[a];
                }
            }
            __syncthreads();

            // --- epilogue (256 threads): 1 row x 2 j; one u32 store ---
            {
                int rbase = (em >> 4) * 2 * 1024;
                union { _Float16 h[2]; unsigned int u; } hv;
#pragma unroll
                for (int jj = 0; jj < 2; ++jj) {
                    int jl = jp * 2 + jj;                      // 0..15
                    int msw = (em & 15) ^ ((jl & 3) << 2);
                    float gi = scr[rbase + (0 * 16 + jl) * 16 + msw] + x * wi_[0][jj] + bs_[0][jj];
                    float gf = scr[rbase + (1 * 16 + jl) * 16 + msw] + x * wi_[1][jj] + bs_[1][jj];
                    float gg = scr[rbase + (2 * 16 + jl) * 16 + msw] + x * wi_[2][jj] + bs_[2][jj];
                    float go = scr[rbase + (3 * 16 + jl) * 16 + msw] + x * wi_[3][jj] + bs_[3][jj];
                    float cn = sigf(gf) * c_[jj] + sigf(gi) * tanhff(gg);
                    float hn = sigf(go) * tanhff(cn);
                    c_[jj] = cn;
                    hv.h[jj] = (_Float16)hn;
                }
                if constexpr (FAST)
                    asm volatile("global_store_dword %0, %1, off sc0"
                                 : : "v"((void*)((unsigned int*)hW + sidx32)), "v"(hv.u) : "memory");
                else
                    asm volatile("global_store_dword %0, %1, off sc0 sc1"
                                 : : "v"((void*)((unsigned int*)hW + sidx32)), "v"(hv.u) : "memory");
            }

            // --- drain stores, then m-group barrier (64 WGs, budget-bounded) ---
            asm volatile("s_waitcnt vmcnt(0)" ::: "memory");
            __syncthreads();
            if (tid == 0) {
                unsigned target = 64u * (unsigned)(t + 1);
                if constexpr (FAST) {
                    __hip_atomic_fetch_add(mycnt, 1u, __ATOMIC_RELAXED,
                                           __HIP_MEMORY_SCOPE_WORKGROUP);
                    while (spin_budget &&
                           __hip_atomic_load(mycnt, __ATOMIC_RELAXED,
                                             __HIP_MEMORY_SCOPE_AGENT) < target) {
                        __builtin_amdgcn_s_sleep(1);
                        --spin_budget;
                    }
                } else {
                    __hip_atomic_fetch_add(mycnt, 1u, __ATOMIC_RELAXED,
                                           __HIP_MEMORY_SCOPE_AGENT);
                    while (spin_budget &&
                           __hip_atomic_load(mycnt, __ATOMIC_RELAXED,
                                             __HIP_MEMORY_SCOPE_AGENT) < target) {
                        __builtin_amdgcn_s_sleep(1);
                        --spin_budget;
                    }
                }
            }
            __syncthreads();
        }
    };
    if (fastmode) mainloop(std::integral_constant<bool, true>{});
    else          mainloop(std::integral_constant<bool, false>{});

    // --- final FC (h final in buffer 0): jt3==0 WGs, wave 0 (32 rows each) ---
    if (jt3 == 0 && k4 == 0) {
        const unsigned long long* hF = hbase;   // buffer 0
#pragma unroll 1
        for (int rr = 0; rr < 32; ++rr) {
            int row = gm * 32 + rr;
            int boff = row;
            float s = 0.f;
#pragma unroll 1
            for (int uu = 0; uu < 4; ++uu) {
                int U = uu * 64 + lane;
                unsigned long long u;
                if (fastmode) {
                    asm volatile("global_load_dwordx2 %0, %1, off sc1\n\ts_waitcnt vmcnt(0)"
                                 : "=v"(u) : "v"(&hF[(size_t)U * 256 + boff]) : "memory");
                } else {
                    u = __hip_atomic_load((unsigned long long*)&hF[(size_t)U * 256 + boff],
                                          __ATOMIC_RELAXED, __HIP_MEMORY_SCOPE_AGENT);
                }
                int kb = (U >> 3) * 32 + ((U >> 1) & 3) * 8 + (U & 1) * 4;
                union { _Float16 h[4]; unsigned long long x; } v;
                v.x = u;
                float4 wf = *(const float4*)(W_fc + kb);
                s += (float)v.h[0] * wf.x + (float)v.h[1] * wf.y +
                     (float)v.h[2] * wf.z + (float)v.h[3] * wf.w;
            }
#pragma unroll
            for (int off = 32; off > 0; off >>= 1) s += __shfl_xor(s, off);
            if (lane == 0) out[row] = s + b_fc[0];
        }
    }
}

extern "C" void kernel_launch(void* const* d_in, const int* in_sizes, int n_in,
                              void* d_out, int out_size, void* d_ws, size_t ws_size,
                              hipStream_t stream) {
    const float* y_hist = (const float*)d_in[0];
    const float* W_ih   = (const float*)d_in[1];
    const float* W_hh   = (const float*)d_in[2];
    const float* b_ih   = (const float*)d_in[3];
    const float* b_hh   = (const float*)d_in[4];
    const float* W_fc   = (const float*)d_in[5];
    const float* b_fc   = (const float*)d_in[6];
    const float* h0     = (const float*)d_in[7];
    const float* c0     = (const float*)d_in[8];
    float* out = (float*)d_out;

    // ws: Wp fp16 (8 MB) | h buffers 2 x 512 KB | cnt (1 KB)
    unsigned short* Wp = (unsigned short*)d_ws;
    unsigned long long* hbase = (unsigned long long*)(Wp + (size_t)4194304);
    unsigned int* cnt = (unsigned int*)(hbase + 2 * HP_U64);

    pack_w<<<2048, 256, 0, stream>>>(W_hh, Wp);
    prep_state<<<256, 256, 0, stream>>>(h0, hbase, cnt);

    // 512 WGs x 256 threads, 16 KiB LDS, <=256 VGPR -> 2 WGs/CU, all co-resident
    lstm_persist<<<512, 256, 0, stream>>>(y_hist, W_ih, b_ih, b_hh, c0, W_fc, b_fc,
                                          Wp, hbase, cnt, out);
}

// Round 8
// 2381.491 us; speedup vs baseline: 1.6016x; 1.6016x over previous
//
#include <hip/hip_runtime.h>
#include <hip/hip_bf16.h>
#include <type_traits>

// LSTM decoder B=256, T=512, H=1024 — persistent fp16 MFMA, v12.
// = v10.3 (2365 us measured, XCD-local h path proven by WRITE 266MB->5MB)
// + ONE change: __attribute__((amdgpu_waves_per_eu(2,2))).
// Evidence (R7): VGPR_Count=120 in v8/v10.3/v11 — but the declared live set
// (Breg 128 + acc 32 + ring 32 + addressing) needs ~220. The allocator was
// capping at 128 VGPR to keep 4 waves/SIMD *possible*, though the 512-thread
// 160KB-LDS WG pins real occupancy at 2 waves/SIMD. Result: Breg was spilled
// and re-fetched ~32x per wave per step inside the K-loop (per-chunk VMEM
// waits -> MfmaUtil stuck at 17%). v11 ("register-resident B") regressed
// because the registers never existed. Pinning waves/EU to 2 gives the
// allocator its real 256-VGPR budget so Breg/ring/acc actually reside.

#define BB 256
#define TT 512
#define HH 1024

typedef __attribute__((ext_vector_type(8))) short short8;
typedef __attribute__((ext_vector_type(8))) _Float16 half8;
typedef __attribute__((ext_vector_type(4))) float float4v;

#define HP_U64 ((size_t)65536)   // u64 per h buffer: 256 U-units x 256 rows

__device__ __forceinline__ float sigf(float x) { return 1.0f / (1.0f + __expf(-x)); }
__device__ __forceinline__ float tanhff(float x) {
    return 1.0f - 2.0f / (__expf(2.0f * x) + 1.0f);
}

// ---- pack W_hh (4096x1024 f32) -> fp16 B-fragment order ----
// Wp[jt2(32)][kc(32)][g(4)][nt(2)][lane(64)][8] ; per-jt2 block = 256 KB
__global__ __launch_bounds__(256) void pack_w(const float* __restrict__ W_hh,
                                              unsigned short* __restrict__ Wp) {
    int fid = blockIdx.x * 256 + threadIdx.x;   // 0..524287
    int lane = fid & 63;
    int nt = (fid >> 6) & 1;
    int g = (fid >> 7) & 3;
    int kc = (fid >> 9) & 31;
    int jt2 = fid >> 14;
    int j = jt2 * 32 + nt * 16 + (lane & 15);
    int row = g * HH + j;
    int k = kc * 32 + (lane >> 4) * 8;
    const float* src = W_hh + (size_t)row * HH + k;
    union { _Float16 h[8]; short8 s; } u;
#pragma unroll
    for (int e = 0; e < 8; ++e) u.h[e] = (_Float16)src[e];
    *(short8*)(Wp + (size_t)fid * 8) = u.s;
}

// ---- h0 -> fp16 fragment layout in buffer 0; zero barrier counters ----
// unit U=(k>>5)*8+((k>>2)&7); u64 idx = U*256 + M  (boff == M)
__global__ __launch_bounds__(256) void prep_state(const float* __restrict__ h0,
                                                  unsigned long long* __restrict__ hb0,
                                                  unsigned int* __restrict__ cnt) {
    int gid = blockIdx.x * 256 + threadIdx.x;   // 0..65535
    int r = gid & 255;
    int U = gid >> 8;
    int kb = (U >> 3) * 32 + ((U >> 1) & 3) * 8 + (U & 1) * 4;
    float4 v = *(const float4*)(h0 + (size_t)r * HH + kb);
    union { _Float16 h[4]; unsigned long long u; } x;
    x.h[0] = (_Float16)v.x; x.h[1] = (_Float16)v.y;
    x.h[2] = (_Float16)v.z; x.h[3] = (_Float16)v.w;
    hb0[(size_t)U * 256 + r] = x.u;
    if (blockIdx.x == 0) cnt[threadIdx.x] = 0;   // per-group {bar, mask, arrive}
}

// ---- persistent LSTM kernel: all 512 steps + final FC ----
__global__ __launch_bounds__(512)
__attribute__((amdgpu_waves_per_eu(2, 2)))
void lstm_persist(
    const float* __restrict__ y_hist,
    const float* __restrict__ W_ih,           // (4096) flat
    const float* __restrict__ b_ih,
    const float* __restrict__ b_hh,
    const float* __restrict__ c0,             // (B,H) f32
    const float* __restrict__ W_fc,           // (H)
    const float* __restrict__ b_fc,           // (1)
    const unsigned short* __restrict__ Wp,    // packed fp16 W fragments
    unsigned long long* hbase,                // 2 buffers x HP_U64 u64
    unsigned int* cnt,
    float* __restrict__ out)
{
    __shared__ __align__(16) unsigned short Wlds[65536];   // 128 KB: gates 0,1
    __shared__ __align__(16) float scr[8192];              // 32 KB: 4 regions x 2048
    // 160 KiB exactly -> 1 WG/CU; grid=256 => all WGs co-resident
    // (mode flag bounced through scr[0]; NO extra __shared__)

    const int tid = threadIdx.x;
    const int lane = tid & 63;
    const int wv = tid >> 6;
    const int m2 = wv & 1;                     // m half (16 rows)
    const int k4 = wv >> 1;                    // K quarter (256 k)
    const int bid = blockIdx.x;
    const int gm = bid & 7;                    // m-group == XCD id (round-robin)
    const int jt2 = bid >> 3;                  // 32-j tile

    const unsigned short* WpJ = Wp + (size_t)jt2 * 131072;

    // --- LDS: gates 0,1 fragments (all kc) ---
    for (int f = tid; f < 8192; f += 512) {
        int kc = f >> 8, g = (f >> 7) & 1, low = f & 127;
        *(short8*)&Wlds[(size_t)((kc * 2 + g) * 128 + low) * 8] =
            *(const short8*)(WpJ + (size_t)((kc * 4 + g) * 128 + low) * 8);
    }
    // --- registers: gates 2,3 fragments for this wave's K-quarter ---
    half8 Breg[8][2][2];   // [kc_l][g-2][nt] — 128 VGPR, now actually resident
#pragma unroll
    for (int kc_l = 0; kc_l < 8; ++kc_l) {
        int kc = k4 * 8 + kc_l;
#pragma unroll
        for (int g2 = 0; g2 < 2; ++g2)
#pragma unroll
            for (int nt = 0; nt < 2; ++nt)
                Breg[kc_l][g2][nt] = *(const half8*)
                    (WpJ + (size_t)((((kc * 4 + 2 + g2) * 2 + nt) * 64 + lane)) * 8);
    }

    // --- A addressing ---
    const int blk = gm * 2 + m2;               // 16-row block 0..15
    const int q = lane >> 4;
    const size_t abase = (size_t)blk * 16 + (lane & 15);
    const size_t qoff = (size_t)q * 512;

    // --- epilogue constants (ALL 512 threads: cell = 1 row x 2 j) ---
    const int em = tid & 31;                   // tile-local row
    const int jp = tid >> 5;                   // j-pair 0..15
    const int jq = jp >> 1;
    const int M = gm * 32 + em;
    float wi_[4][2], bs_[4][2], c_[2];
#pragma unroll
    for (int g = 0; g < 4; ++g)
#pragma unroll
        for (int jj = 0; jj < 2; ++jj) {
            int j = jt2 * 32 + jp * 2 + jj;
            wi_[g][jj] = W_ih[g * HH + j];
            bs_[g][jj] = b_ih[g * HH + j] + b_hh[g * HH + j];
        }
#pragma unroll
    for (int jj = 0; jj < 2; ++jj)
        c_[jj] = c0[(size_t)M * HH + jt2 * 32 + jp * 2 + jj];
    // u32 store index: ((jt2*8+jq)*256 + M)*2 + (jp&1); wave = full 256B line
    const size_t sidx32 = ((size_t)(jt2 * 8 + jq) * 256 + M) * 2 + (jp & 1);

    __syncthreads();   // Wlds visible

    unsigned int* mycnt = cnt + gm * 32;       // [0]=barrier [1]=xcd mask [2]=arrive
    const int ml = q * 4;                      // local row base within 16-row tile

    // --- spin budget: hang-proofing (v10.3-proven) ---
    unsigned spin_budget = 1u << 20;

    // --- XCD-uniformity detection (device-scope, once). Bailout -> SAFE. ---
    if (tid == 0) {
        unsigned myxcd;
        asm volatile("s_getreg_b32 %0, hwreg(HW_REG_XCC_ID)" : "=s"(myxcd));
        __hip_atomic_fetch_or(mycnt + 1, 1u << (myxcd & 31u),
                              __ATOMIC_RELAXED, __HIP_MEMORY_SCOPE_AGENT);
        __hip_atomic_fetch_add(mycnt + 2, 1u,
                               __ATOMIC_RELAXED, __HIP_MEMORY_SCOPE_AGENT);
        int ok = 0;
        while (spin_budget) {
            if (__hip_atomic_load(mycnt + 2, __ATOMIC_RELAXED,
                                  __HIP_MEMORY_SCOPE_AGENT) >= 32u) { ok = 1; break; }
            __builtin_amdgcn_s_sleep(1);
            --spin_budget;
        }
        unsigned mm = __hip_atomic_load(mycnt + 1, __ATOMIC_RELAXED,
                                        __HIP_MEMORY_SCOPE_AGENT);
        ((volatile int*)scr)[0] = (ok && ((mm & (mm - 1u)) == 0u)) ? 1 : 0;
    }
    __syncthreads();
    const bool fastmode = (((volatile int*)scr)[0] != 0);
    __syncthreads();   // flag captured before scr reuse

    auto mainloop = [&](auto FASTC) {
        constexpr bool FAST = decltype(FASTC)::value;
        for (int t = 0; t < TT; ++t) {
            const unsigned long long* hR = hbase + (size_t)(t & 1) * HP_U64;
            unsigned long long* hW = hbase + (size_t)((t + 1) & 1) * HP_U64;

            // prefetch y_hist x (consumed in epilogue; hides under K-loop)
            float x = y_hist[(size_t)M * TT + t];

            float4v acc[8] = {{0.f,0.f,0.f,0.f},{0.f,0.f,0.f,0.f},{0.f,0.f,0.f,0.f},
                              {0.f,0.f,0.f,0.f},{0.f,0.f,0.f,0.f},{0.f,0.f,0.f,0.f},
                              {0.f,0.f,0.f,0.f},{0.f,0.f,0.f,0.f}};

            // --- sync-free K-loop: 8 chunks of K=32, FULL 8-deep prefetch ring ---
            unsigned long long ring[8][2];
            if constexpr (FAST) {
                // sc1: device scope — probes the (same-XCD) L2, hits dirty
                // lines from fastmode stores; bypasses possibly-stale L1.
#pragma unroll
                for (int p = 0; p < 8; ++p) {
                    size_t ua = (size_t)(k4 * 8 + p) * 2048 + qoff + abase;
                    asm volatile("global_load_dwordx2 %0, %1, off sc1"
                                 : "=v"(ring[p][0]) : "v"(&hR[ua]));
                    asm volatile("global_load_dwordx2 %0, %1, off sc1"
                                 : "=v"(ring[p][1]) : "v"(&hR[ua + 256]));
                }
                asm volatile("s_waitcnt vmcnt(0)" ::: "memory");
                __builtin_amdgcn_sched_barrier(0);   // rule #18: pin uses after wait
            } else {
#pragma unroll
                for (int p = 0; p < 8; ++p) {
                    size_t ua = (size_t)(k4 * 8 + p) * 2048 + qoff + abase;
                    ring[p][0] = __hip_atomic_load((unsigned long long*)&hR[ua],
                                                   __ATOMIC_RELAXED, __HIP_MEMORY_SCOPE_AGENT);
                    ring[p][1] = __hip_atomic_load((unsigned long long*)&hR[ua + 256],
                                                   __ATOMIC_RELAXED, __HIP_MEMORY_SCOPE_AGENT);
                }
            }
#pragma unroll
            for (int ch = 0; ch < 8; ++ch) {
                union { unsigned long long u[2]; half8 h; } af;
                af.u[0] = ring[ch][0];
                af.u[1] = ring[ch][1];
                const int kc = k4 * 8 + ch;
#pragma unroll
                for (int g = 0; g < 2; ++g)
#pragma unroll
                    for (int nt = 0; nt < 2; ++nt) {
                        half8 bh = *(const half8*)
                            &Wlds[(size_t)((kc * 2 + g) * 128 + nt * 64 + lane) * 8];
                        acc[g * 2 + nt] =
                            __builtin_amdgcn_mfma_f32_16x16x32_f16(af.h, bh, acc[g * 2 + nt], 0, 0, 0);
                    }
#pragma unroll
                for (int g2 = 0; g2 < 2; ++g2)
#pragma unroll
                    for (int nt = 0; nt < 2; ++nt)
                        acc[(2 + g2) * 2 + nt] =
                            __builtin_amdgcn_mfma_f32_16x16x32_f16(af.h, Breg[ch][g2][nt],
                                                                   acc[(2 + g2) * 2 + nt], 0, 0, 0);
            }

            // --- 4-way k-reduction, 2 rounds in 32 KB scratch (v6-proven) ---
            if (k4 >= 2) {
                int rb = (m2 * 2 + (k4 & 1)) * 2048;
#pragma unroll
                for (int a = 0; a < 8; ++a) {
                    int n = (a >> 1) * 32 + (a & 1) * 16 + (lane & 15);
                    *(float4v*)&scr[rb + n * 16 + (ml ^ ((n & 3) << 2))] = acc[a];
                }
            }
            __syncthreads();
            if (k4 < 2) {
                int rb = (m2 * 2 + k4) * 2048;
#pragma unroll
                for (int a = 0; a < 8; ++a) {
                    int n = (a >> 1) * 32 + (a & 1) * 16 + (lane & 15);
                    acc[a] += *(const float4v*)&scr[rb + n * 16 + (ml ^ ((n & 3) << 2))];
                }
                if (k4 == 1) {
#pragma unroll
                    for (int a = 0; a < 8; ++a) {
                        int n = (a >> 1) * 32 + (a & 1) * 16 + (lane & 15);
                        *(float4v*)&scr[(m2 * 2 + 1) * 2048 + n * 16 + (ml ^ ((n & 3) << 2))] = acc[a];
                    }
                }
            }
            __syncthreads();
            if (k4 == 0) {
#pragma unroll
                for (int a = 0; a < 8; ++a) {
                    int n = (a >> 1) * 32 + (a & 1) * 16 + (lane & 15);
                    int sw = n * 16 + (ml ^ ((n & 3) << 2));
                    acc[a] += *(const float4v*)&scr[(m2 * 2 + 1) * 2048 + sw];
                    *(float4v*)&scr[(m2 * 2) * 2048 + sw] = acc[a];
                }
            }
            __syncthreads();

            // --- epilogue (all 512 threads): 1 row x 2 j; one u32 store ---
            {
                int rbase = (em >> 4) * 2 * 2048;
                union { _Float16 h[2]; unsigned int u; } hv;
#pragma unroll
                for (int jj = 0; jj < 2; ++jj) {
                    int jl = jp * 2 + jj;                      // 0..31
                    int msw = (em & 15) ^ ((jl & 3) << 2);
                    float gi = scr[rbase + (0 * 32 + jl) * 16 + msw] + x * wi_[0][jj] + bs_[0][jj];
                    float gf = scr[rbase + (1 * 32 + jl) * 16 + msw] + x * wi_[1][jj] + bs_[1][jj];
                    float gg = scr[rbase + (2 * 32 + jl) * 16 + msw] + x * wi_[2][jj] + bs_[2][jj];
                    float go = scr[rbase + (3 * 32 + jl) * 16 + msw] + x * wi_[3][jj] + bs_[3][jj];
                    float cn = sigf(gf) * c_[jj] + sigf(gi) * tanhff(gg);
                    float hn = sigf(go) * tanhff(cn);
                    c_[jj] = cn;
                    hv.h[jj] = (_Float16)hn;
                }
                if constexpr (FAST)
                    asm volatile("global_store_dword %0, %1, off sc0"
                                 : : "v"((void*)((unsigned int*)hW + sidx32)), "v"(hv.u) : "memory");
                else
                    asm volatile("global_store_dword %0, %1, off sc0 sc1"
                                 : : "v"((void*)((unsigned int*)hW + sidx32)), "v"(hv.u) : "memory");
            }

            // --- drain stores, then m-group barrier (32 WGs, budget-bounded) ---
            asm volatile("s_waitcnt vmcnt(0)" ::: "memory");
            __syncthreads();
            if (tid == 0) {
                unsigned target = 32u * (unsigned)(t + 1);
                if constexpr (FAST) {
                    __hip_atomic_fetch_add(mycnt, 1u, __ATOMIC_RELAXED,
                                           __HIP_MEMORY_SCOPE_WORKGROUP);
                    while (spin_budget &&
                           __hip_atomic_load(mycnt, __ATOMIC_RELAXED,
                                             __HIP_MEMORY_SCOPE_AGENT) < target) {
                        __builtin_amdgcn_s_sleep(1);
                        --spin_budget;
                    }
                } else {
                    __hip_atomic_fetch_add(mycnt, 1u, __ATOMIC_RELAXED,
                                           __HIP_MEMORY_SCOPE_AGENT);
                    while (spin_budget &&
                           __hip_atomic_load(mycnt, __ATOMIC_RELAXED,
                                             __HIP_MEMORY_SCOPE_AGENT) < target) {
                        __builtin_amdgcn_s_sleep(1);
                        --spin_budget;
                    }
                }
            }
            __syncthreads();
        }
    };
    if (fastmode) mainloop(std::integral_constant<bool, true>{});
    else          mainloop(std::integral_constant<bool, false>{});

    // --- final FC (h final in buffer 0): jt2==0 WGs, k4==0 waves ---
    if (jt2 == 0 && k4 == 0) {
        const unsigned long long* hF = hbase;   // buffer 0
#pragma unroll 1
        for (int rr = 0; rr < 16; ++rr) {
            int row = gm * 32 + m2 * 16 + rr;
            int boff = row;                     // boff == M
            float s = 0.f;
#pragma unroll 1
            for (int uu = 0; uu < 4; ++uu) {
                int U = uu * 64 + lane;
                unsigned long long u;
                if (fastmode) {
                    asm volatile("global_load_dwordx2 %0, %1, off sc1\n\ts_waitcnt vmcnt(0)"
                                 : "=v"(u) : "v"(&hF[(size_t)U * 256 + boff]) : "memory");
                } else {
                    u = __hip_atomic_load((unsigned long long*)&hF[(size_t)U * 256 + boff],
                                          __ATOMIC_RELAXED, __HIP_MEMORY_SCOPE_AGENT);
                }
                int kb = (U >> 3) * 32 + ((U >> 1) & 3) * 8 + (U & 1) * 4;
                union { _Float16 h[4]; unsigned long long x; } v;
                v.x = u;
                float4 wf = *(const float4*)(W_fc + kb);
                s += (float)v.h[0] * wf.x + (float)v.h[1] * wf.y +
                     (float)v.h[2] * wf.z + (float)v.h[3] * wf.w;
            }
#pragma unroll
            for (int off = 32; off > 0; off >>= 1) s += __shfl_xor(s, off);
            if (lane == 0) out[row] = s + b_fc[0];
        }
    }
}

extern "C" void kernel_launch(void* const* d_in, const int* in_sizes, int n_in,
                              void* d_out, int out_size, void* d_ws, size_t ws_size,
                              hipStream_t stream) {
    const float* y_hist = (const float*)d_in[0];
    const float* W_ih   = (const float*)d_in[1];
    const float* W_hh   = (const float*)d_in[2];
    const float* b_ih   = (const float*)d_in[3];
    const float* b_hh   = (const float*)d_in[4];
    const float* W_fc   = (const float*)d_in[5];
    const float* b_fc   = (const float*)d_in[6];
    const float* h0     = (const float*)d_in[7];
    const float* c0     = (const float*)d_in[8];
    float* out = (float*)d_out;

    // ws: Wp fp16 (8 MB) | h buffers 2 x 512 KB | cnt (1 KB)
    unsigned short* Wp = (unsigned short*)d_ws;
    unsigned long long* hbase = (unsigned long long*)(Wp + (size_t)4194304);
    unsigned int* cnt = (unsigned int*)(hbase + 2 * HP_U64);

    pack_w<<<2048, 256, 0, stream>>>(W_hh, Wp);
    prep_state<<<256, 256, 0, stream>>>(h0, hbase, cnt);

    // 256 WGs x 512 threads, 160 KiB LDS -> 1 WG/CU, all co-resident
    lstm_persist<<<256, 512, 0, stream>>>(y_hist, W_ih, b_ih, b_hh, c0, W_fc, b_fc,
                                          Wp, hbase, cnt, out);
}